// Round 6
// baseline (149.869 us; speedup 1.0000x reference)
//
#include <hip/hip_runtime.h>

// Problem constants (match reference setup)
#define N_NODES   131072
#define N_EDGES   8388608
#define N_CLASSES 16
#define N_BATCH   4

// Fast-path histogram geometry
#define N_SLICES        256
#define EDGES_PER_SLICE (N_EDGES / N_SLICES)   // 32768
#define HIST_WORDS      (N_NODES / 4)          // 32768 u32 words = 131072 u8 bins = 128 KB

typedef int v4i __attribute__((ext_vector_type(4)));

// bf16 helpers
__device__ __forceinline__ unsigned f2bf(float f) {
    unsigned x = __float_as_uint(f);
    return (x + 0x7FFFu + ((x >> 16) & 1u)) >> 16;   // RNE; data has no NaN/Inf
}
__device__ __forceinline__ float bf_lo(unsigned w) { return __uint_as_float(w << 16); }
__device__ __forceinline__ float bf_hi(unsigned w) { return __uint_as_float(w & 0xFFFF0000u); }

// ===========================================================================
// FAST PATH
// ===========================================================================

// ---------------------------------------------------------------------------
// K1: per-slice u8-packed LDS histogram of src. No global atomics.
// 256 slices -> one block per CU; per-slice per-bin count <= ~8 (u8 safe).
// ---------------------------------------------------------------------------
__global__ __launch_bounds__(1024)
void hist_kernel(const int* __restrict__ src, unsigned int* __restrict__ partials) {
    __shared__ unsigned int hist[HIST_WORDS];  // 128 KB
    uint4* h4 = (uint4*)hist;
    #pragma unroll
    for (int i = threadIdx.x; i < HIST_WORDS / 4; i += 1024)
        h4[i] = make_uint4(0u, 0u, 0u, 0u);
    __syncthreads();

    const int slice = blockIdx.x;
    const v4i* s4 = (const v4i*)(src + slice * EDGES_PER_SLICE);
    #pragma unroll
    for (int i = threadIdx.x; i < EDGES_PER_SLICE / 4; i += 1024) {
        v4i v = __builtin_nontemporal_load(s4 + i);
        atomicAdd(&hist[v[0] >> 2], 1u << ((v[0] & 3) << 3));
        atomicAdd(&hist[v[1] >> 2], 1u << ((v[1] & 3) << 3));
        atomicAdd(&hist[v[2] >> 2], 1u << ((v[2] & 3) << 3));
        atomicAdd(&hist[v[3] >> 2], 1u << ((v[3] & 3) << 3));
    }
    __syncthreads();

    uint4* p4 = (uint4*)(partials + (size_t)slice * HIST_WORDS);
    #pragma unroll
    for (int i = threadIdx.x; i < HIST_WORDS / 4; i += 1024)
        p4[i] = h4[i];
}

// ---------------------------------------------------------------------------
// K2: reduce partials -> deg; dscale = deg^-1/2; xs0 = feat0*dscale (f32);
// u[n][16] = dscale[n]*fc_w[:,n] packed bf16x2 -> 8 u32 per node (32 B row).
// ---------------------------------------------------------------------------
__global__ __launch_bounds__(256)
void reduce_finalize_kernel(const unsigned int* __restrict__ partials,
                            const float* __restrict__ feat0,
                            const float* __restrict__ fc_w,
                            uint4* __restrict__ ub4,     // [N_NODES*2] uint4
                            float* __restrict__ xs0) {
    int t = blockIdx.x * 256 + threadIdx.x;   // 0..32767, nodes 4t..4t+3
    unsigned d0 = 0, d1 = 0, d2 = 0, d3 = 0;
    #pragma unroll 8
    for (int s = 0; s < N_SLICES; ++s) {
        unsigned p = partials[(size_t)s * HIST_WORDS + t];
        d0 += p & 255u;
        d1 += (p >> 8) & 255u;
        d2 += (p >> 16) & 255u;
        d3 += (p >> 24);
    }
    float dsx = rsqrtf((float)d0);
    float dsy = rsqrtf((float)d1);
    float dsz = rsqrtf((float)d2);
    float dsw = rsqrtf((float)d3);

    float4 f = ((const float4*)feat0)[t];
    ((float4*)xs0)[t] = make_float4(f.x * dsx, f.y * dsy, f.z * dsz, f.w * dsw);

    float row0[16], row1[16], row2[16], row3[16];
    #pragma unroll
    for (int c = 0; c < N_CLASSES; ++c) {
        float4 w = ((const float4*)(fc_w + (size_t)c * N_NODES))[t];
        row0[c] = dsx * w.x;
        row1[c] = dsy * w.y;
        row2[c] = dsz * w.z;
        row3[c] = dsw * w.w;
    }
    size_t base = (size_t)(4 * t) * 2;  // uint4 index of node (4t)'s row
    #pragma unroll
    for (int k = 0; k < 2; ++k)
        ub4[base + k] = make_uint4(
            f2bf(row0[8*k+0]) | (f2bf(row0[8*k+1]) << 16),
            f2bf(row0[8*k+2]) | (f2bf(row0[8*k+3]) << 16),
            f2bf(row0[8*k+4]) | (f2bf(row0[8*k+5]) << 16),
            f2bf(row0[8*k+6]) | (f2bf(row0[8*k+7]) << 16));
    #pragma unroll
    for (int k = 0; k < 2; ++k)
        ub4[base + 2 + k] = make_uint4(
            f2bf(row1[8*k+0]) | (f2bf(row1[8*k+1]) << 16),
            f2bf(row1[8*k+2]) | (f2bf(row1[8*k+3]) << 16),
            f2bf(row1[8*k+4]) | (f2bf(row1[8*k+5]) << 16),
            f2bf(row1[8*k+6]) | (f2bf(row1[8*k+7]) << 16));
    #pragma unroll
    for (int k = 0; k < 2; ++k)
        ub4[base + 4 + k] = make_uint4(
            f2bf(row2[8*k+0]) | (f2bf(row2[8*k+1]) << 16),
            f2bf(row2[8*k+2]) | (f2bf(row2[8*k+3]) << 16),
            f2bf(row2[8*k+4]) | (f2bf(row2[8*k+5]) << 16),
            f2bf(row2[8*k+6]) | (f2bf(row2[8*k+7]) << 16));
    #pragma unroll
    for (int k = 0; k < 2; ++k)
        ub4[base + 6 + k] = make_uint4(
            f2bf(row3[8*k+0]) | (f2bf(row3[8*k+1]) << 16),
            f2bf(row3[8*k+2]) | (f2bf(row3[8*k+3]) << 16),
            f2bf(row3[8*k+4]) | (f2bf(row3[8*k+5]) << 16),
            f2bf(row3[8*k+6]) | (f2bf(row3[8*k+7]) << 16));
}

// ---------------------------------------------------------------------------
// K3: init out with fc_b (all 4 batch rows; rows 1..3 keep this value)
// ---------------------------------------------------------------------------
__global__ void out_init_kernel(const float* __restrict__ fc_b, float* __restrict__ out) {
    int t = threadIdx.x;  // 64 threads
    if (t < N_BATCH * N_CLASSES) out[t] = fc_b[t & (N_CLASSES - 1)];
}

// ---------------------------------------------------------------------------
// K4: out[0,c] += sum_{e: src in [lo,hi)} u_bf16[src[e]][c] * xs0[dst[e]]
// Src-range-filtered pass: live u-slice = (hi-lo)*32B; with hi-lo = N/2 the
// hot set is 2 MiB + xs0 0.5 MB -> resident in the 4 MiB per-XCD L2.
// Edges streamed with nt loads (no L2 pollution).
// ---------------------------------------------------------------------------
__global__ __launch_bounds__(256)
void gather_kernel(const int* __restrict__ src, const int* __restrict__ dst,
                   const float* __restrict__ xs0, const uint4* __restrict__ ub4,
                   float* __restrict__ out, int lo, int hi) {
    const v4i* s4 = (const v4i*)src;
    const v4i* d4 = (const v4i*)dst;

    float acc[N_CLASSES];
    #pragma unroll
    for (int c = 0; c < N_CLASSES; ++c) acc[c] = 0.0f;

    const int stride = 2048 * 256;
    int tid = blockIdx.x * 256 + threadIdx.x;

    for (int i = tid; i < N_EDGES / 4; i += stride) {
        v4i s = __builtin_nontemporal_load(s4 + i);
        v4i d = __builtin_nontemporal_load(d4 + i);

        #define EDGE(SS, DD)                                                   \
        if ((SS) >= lo && (SS) < hi) {                                         \
            float x = xs0[DD];                                                 \
            size_t b = (size_t)(SS) * 2;                                       \
            uint4 r0 = ub4[b], r1 = ub4[b + 1];                                \
            acc[0]  = fmaf(bf_lo(r0.x), x, acc[0]);                            \
            acc[1]  = fmaf(bf_hi(r0.x), x, acc[1]);                            \
            acc[2]  = fmaf(bf_lo(r0.y), x, acc[2]);                            \
            acc[3]  = fmaf(bf_hi(r0.y), x, acc[3]);                            \
            acc[4]  = fmaf(bf_lo(r0.z), x, acc[4]);                            \
            acc[5]  = fmaf(bf_hi(r0.z), x, acc[5]);                            \
            acc[6]  = fmaf(bf_lo(r0.w), x, acc[6]);                            \
            acc[7]  = fmaf(bf_hi(r0.w), x, acc[7]);                            \
            acc[8]  = fmaf(bf_lo(r1.x), x, acc[8]);                            \
            acc[9]  = fmaf(bf_hi(r1.x), x, acc[9]);                            \
            acc[10] = fmaf(bf_lo(r1.y), x, acc[10]);                           \
            acc[11] = fmaf(bf_hi(r1.y), x, acc[11]);                           \
            acc[12] = fmaf(bf_lo(r1.z), x, acc[12]);                           \
            acc[13] = fmaf(bf_hi(r1.z), x, acc[13]);                           \
            acc[14] = fmaf(bf_lo(r1.w), x, acc[14]);                           \
            acc[15] = fmaf(bf_hi(r1.w), x, acc[15]);                           \
        }
        EDGE(s[0], d[0])
        EDGE(s[1], d[1])
        EDGE(s[2], d[2])
        EDGE(s[3], d[3])
        #undef EDGE
    }

    // wave64 butterfly reduce each class, then block partials, then 16 atomics
    __shared__ float part[4][N_CLASSES];
    int lane = threadIdx.x & 63;
    int wid  = threadIdx.x >> 6;
    #pragma unroll
    for (int c = 0; c < N_CLASSES; ++c) {
        float v = acc[c];
        #pragma unroll
        for (int off = 32; off > 0; off >>= 1) v += __shfl_down(v, off, 64);
        if (lane == 0) part[wid][c] = v;
    }
    __syncthreads();
    if (threadIdx.x < N_CLASSES) {
        int c = threadIdx.x;
        float sum = part[0][c] + part[1][c] + part[2][c] + part[3][c];
        atomicAdd(&out[c], sum);
    }
}

// ===========================================================================
// FALLBACK PATH (ws too small): proven-correct baseline with global atomics
// ===========================================================================
__global__ void deg_kernel(const int* __restrict__ src, unsigned int* __restrict__ deg) {
    const int4* src4 = (const int4*)src;
    int stride = gridDim.x * blockDim.x;
    for (int i = blockIdx.x * blockDim.x + threadIdx.x; i < N_EDGES / 4; i += stride) {
        int4 s = src4[i];
        atomicAdd(&deg[s.x], 1u); atomicAdd(&deg[s.y], 1u);
        atomicAdd(&deg[s.z], 1u); atomicAdd(&deg[s.w], 1u);
    }
}
__global__ void scale_kernel(const float* __restrict__ feat0,
                             const unsigned int* __restrict__ deg,
                             float* __restrict__ dscale, float* __restrict__ xs0) {
    int n = blockIdx.x * blockDim.x + threadIdx.x;
    if (n < N_NODES) {
        float ds = rsqrtf((float)deg[n]);
        dscale[n] = ds;
        xs0[n] = feat0[n] * ds;
    }
}
__global__ void scatter_kernel(const int* __restrict__ src, const int* __restrict__ dst,
                               const float* __restrict__ xs0, float* __restrict__ agg0) {
    const int4* src4 = (const int4*)src;
    const int4* dst4 = (const int4*)dst;
    int stride = gridDim.x * blockDim.x;
    for (int i = blockIdx.x * blockDim.x + threadIdx.x; i < N_EDGES / 4; i += stride) {
        int4 s = src4[i]; int4 d = dst4[i];
        atomicAdd(&agg0[s.x], xs0[d.x]); atomicAdd(&agg0[s.y], xs0[d.y]);
        atomicAdd(&agg0[s.z], xs0[d.z]); atomicAdd(&agg0[s.w], xs0[d.w]);
    }
}
__global__ void dot_kernel(const float* __restrict__ agg0, const float* __restrict__ dscale,
                           const float* __restrict__ fc_w, float* __restrict__ out) {
    int n = blockIdx.x * blockDim.x + threadIdx.x;
    float y = agg0[n] * dscale[n];
    __shared__ float part[4][N_CLASSES];
    int lane = threadIdx.x & 63, wid = threadIdx.x >> 6;
    #pragma unroll
    for (int c = 0; c < N_CLASSES; ++c) {
        float v = y * fc_w[c * N_NODES + n];
        #pragma unroll
        for (int off = 32; off > 0; off >>= 1) v += __shfl_down(v, off, 64);
        if (lane == 0) part[wid][c] = v;
    }
    __syncthreads();
    if (threadIdx.x < N_CLASSES) {
        int c = threadIdx.x;
        atomicAdd(&out[c], part[0][c] + part[1][c] + part[2][c] + part[3][c]);
    }
}

// ===========================================================================
extern "C" void kernel_launch(void* const* d_in, const int* in_sizes, int n_in,
                              void* d_out, int out_size, void* d_ws, size_t ws_size,
                              hipStream_t stream) {
    const float* nodes_feat = (const float*)d_in[0];   // (B,N,1): batch0 = first N
    const float* fc_w       = (const float*)d_in[1];   // (C,N)
    const float* fc_b       = (const float*)d_in[2];   // (C,)
    const int*   edges      = (const int*)d_in[3];     // (B,2,E): graph 0 only

    const int* src = edges;
    const int* dst = edges + N_EDGES;
    float* out = (float*)d_out;

    // fast path ws: partials 32MB | ub 4MB | xs0 0.5MB
    const size_t PARTIALS_WORDS = (size_t)N_SLICES * HIST_WORDS;        // 8M u32
    const size_t U_WORDS        = (size_t)N_NODES * 8;                  // 1M u32 (bf16x2)
    const size_t NEED = (PARTIALS_WORDS + U_WORDS + N_NODES) * 4;       // ~36.5 MB

    if (ws_size >= NEED) {
        unsigned int* partials = (unsigned int*)d_ws;
        uint4* ub4 = (uint4*)((unsigned int*)d_ws + PARTIALS_WORDS);
        float* xs0 = (float*)((unsigned int*)d_ws + PARTIALS_WORDS + U_WORDS);

        hist_kernel<<<N_SLICES, 1024, 0, stream>>>(src, partials);
        reduce_finalize_kernel<<<N_NODES / 4 / 256, 256, 0, stream>>>(
            partials, nodes_feat, fc_w, ub4, xs0);
        out_init_kernel<<<1, 64, 0, stream>>>(fc_b, out);
        // Two src-range passes: live u-slice 2 MiB each -> per-XCD L2 resident.
        gather_kernel<<<2048, 256, 0, stream>>>(src, dst, xs0, ub4, out,
                                                0, N_NODES / 2);
        gather_kernel<<<2048, 256, 0, stream>>>(src, dst, xs0, ub4, out,
                                                N_NODES / 2, N_NODES);
    } else {
        // fallback: baseline with global atomics (needs 2 MB)
        unsigned int* deg = (unsigned int*)d_ws;
        float* dscale = (float*)d_ws + N_NODES;
        float* xs0    = (float*)d_ws + 2 * N_NODES;
        float* agg0   = (float*)d_ws + 3 * N_NODES;
        hipMemsetAsync(deg, 0, N_NODES * sizeof(unsigned int), stream);
        hipMemsetAsync(agg0, 0, N_NODES * sizeof(float), stream);
        deg_kernel<<<2048, 256, 0, stream>>>(src, deg);
        scale_kernel<<<N_NODES / 256, 256, 0, stream>>>(nodes_feat, deg, dscale, xs0);
        scatter_kernel<<<2048, 256, 0, stream>>>(src, dst, xs0, agg0);
        out_init_kernel<<<1, 64, 0, stream>>>(fc_b, out);
        dot_kernel<<<N_NODES / 256, 256, 0, stream>>>(agg0, dscale, fc_w, out);
    }
}

// Round 7
// 126.542 us; speedup vs baseline: 1.1843x; 1.1843x over previous
//
#include <hip/hip_runtime.h>

// Problem constants (match reference setup)
#define N_NODES   131072
#define N_EDGES   8388608
#define N_CLASSES 16
#define N_BATCH   4

// Fast-path histogram geometry
#define N_SLICES        256
#define EDGES_PER_SLICE (N_EDGES / N_SLICES)   // 32768
#define HIST_WORDS      (N_NODES / 4)          // 32768 u32 words = 131072 u8 bins = 128 KB

typedef int v4i __attribute__((ext_vector_type(4)));

// bf16 helpers
__device__ __forceinline__ unsigned f2bf(float f) {
    unsigned x = __float_as_uint(f);
    return (x + 0x7FFFu + ((x >> 16) & 1u)) >> 16;   // RNE; data has no NaN/Inf
}
__device__ __forceinline__ float bf_lo(unsigned w) { return __uint_as_float(w << 16); }
__device__ __forceinline__ float bf_hi(unsigned w) { return __uint_as_float(w & 0xFFFF0000u); }

// ===========================================================================
// FAST PATH
// ===========================================================================

// ---------------------------------------------------------------------------
// K1: per-slice u8-packed LDS histogram of src. No global atomics.
// ---------------------------------------------------------------------------
__global__ __launch_bounds__(1024)
void hist_kernel(const int* __restrict__ src, unsigned int* __restrict__ partials) {
    __shared__ unsigned int hist[HIST_WORDS];  // 128 KB
    uint4* h4 = (uint4*)hist;
    #pragma unroll
    for (int i = threadIdx.x; i < HIST_WORDS / 4; i += 1024)
        h4[i] = make_uint4(0u, 0u, 0u, 0u);
    __syncthreads();

    const int slice = blockIdx.x;
    const v4i* s4 = (const v4i*)(src + slice * EDGES_PER_SLICE);
    #pragma unroll
    for (int i = threadIdx.x; i < EDGES_PER_SLICE / 4; i += 1024) {
        v4i v = __builtin_nontemporal_load(s4 + i);
        atomicAdd(&hist[v[0] >> 2], 1u << ((v[0] & 3) << 3));
        atomicAdd(&hist[v[1] >> 2], 1u << ((v[1] & 3) << 3));
        atomicAdd(&hist[v[2] >> 2], 1u << ((v[2] & 3) << 3));
        atomicAdd(&hist[v[3] >> 2], 1u << ((v[3] & 3) << 3));
    }
    __syncthreads();

    uint4* p4 = (uint4*)(partials + (size_t)slice * HIST_WORDS);
    #pragma unroll
    for (int i = threadIdx.x; i < HIST_WORDS / 4; i += 1024)
        p4[i] = h4[i];
}

// ---------------------------------------------------------------------------
// K2: reduce partials -> deg; dscale = deg^-1/2; xs0 = feat0*dscale (f32);
// u[n][16] = dscale[n]*fc_w[:,n] packed bf16x2 -> 8 u32 per node (32 B row).
// ---------------------------------------------------------------------------
__global__ __launch_bounds__(256)
void reduce_finalize_kernel(const unsigned int* __restrict__ partials,
                            const float* __restrict__ feat0,
                            const float* __restrict__ fc_w,
                            uint4* __restrict__ ub4,     // [N_NODES*2] uint4
                            float* __restrict__ xs0) {
    int t = blockIdx.x * 256 + threadIdx.x;   // 0..32767, nodes 4t..4t+3
    unsigned d0 = 0, d1 = 0, d2 = 0, d3 = 0;
    #pragma unroll 8
    for (int s = 0; s < N_SLICES; ++s) {
        unsigned p = partials[(size_t)s * HIST_WORDS + t];
        d0 += p & 255u;
        d1 += (p >> 8) & 255u;
        d2 += (p >> 16) & 255u;
        d3 += (p >> 24);
    }
    float dsx = rsqrtf((float)d0);
    float dsy = rsqrtf((float)d1);
    float dsz = rsqrtf((float)d2);
    float dsw = rsqrtf((float)d3);

    float4 f = ((const float4*)feat0)[t];
    ((float4*)xs0)[t] = make_float4(f.x * dsx, f.y * dsy, f.z * dsz, f.w * dsw);

    float row0[16], row1[16], row2[16], row3[16];
    #pragma unroll
    for (int c = 0; c < N_CLASSES; ++c) {
        float4 w = ((const float4*)(fc_w + (size_t)c * N_NODES))[t];
        row0[c] = dsx * w.x;
        row1[c] = dsy * w.y;
        row2[c] = dsz * w.z;
        row3[c] = dsw * w.w;
    }
    size_t base = (size_t)(4 * t) * 2;  // uint4 index of node (4t)'s row
    #pragma unroll
    for (int k = 0; k < 2; ++k)
        ub4[base + k] = make_uint4(
            f2bf(row0[8*k+0]) | (f2bf(row0[8*k+1]) << 16),
            f2bf(row0[8*k+2]) | (f2bf(row0[8*k+3]) << 16),
            f2bf(row0[8*k+4]) | (f2bf(row0[8*k+5]) << 16),
            f2bf(row0[8*k+6]) | (f2bf(row0[8*k+7]) << 16));
    #pragma unroll
    for (int k = 0; k < 2; ++k)
        ub4[base + 2 + k] = make_uint4(
            f2bf(row1[8*k+0]) | (f2bf(row1[8*k+1]) << 16),
            f2bf(row1[8*k+2]) | (f2bf(row1[8*k+3]) << 16),
            f2bf(row1[8*k+4]) | (f2bf(row1[8*k+5]) << 16),
            f2bf(row1[8*k+6]) | (f2bf(row1[8*k+7]) << 16));
    #pragma unroll
    for (int k = 0; k < 2; ++k)
        ub4[base + 4 + k] = make_uint4(
            f2bf(row2[8*k+0]) | (f2bf(row2[8*k+1]) << 16),
            f2bf(row2[8*k+2]) | (f2bf(row2[8*k+3]) << 16),
            f2bf(row2[8*k+4]) | (f2bf(row2[8*k+5]) << 16),
            f2bf(row2[8*k+6]) | (f2bf(row2[8*k+7]) << 16));
    #pragma unroll
    for (int k = 0; k < 2; ++k)
        ub4[base + 6 + k] = make_uint4(
            f2bf(row3[8*k+0]) | (f2bf(row3[8*k+1]) << 16),
            f2bf(row3[8*k+2]) | (f2bf(row3[8*k+3]) << 16),
            f2bf(row3[8*k+4]) | (f2bf(row3[8*k+5]) << 16),
            f2bf(row3[8*k+6]) | (f2bf(row3[8*k+7]) << 16));
}

// ---------------------------------------------------------------------------
// K3: init out with fc_b (all 4 batch rows; rows 1..3 keep this value)
// ---------------------------------------------------------------------------
__global__ void out_init_kernel(const float* __restrict__ fc_b, float* __restrict__ out) {
    int t = threadIdx.x;  // 64 threads
    if (t < N_BATCH * N_CLASSES) out[t] = fc_b[t & (N_CLASSES - 1)];
}

// ---------------------------------------------------------------------------
// K4: out[0,c] += sum_e u_bf16[src[e]][c] * xs0[dst[e]]
// Single pass, MLP-restructured: 8 edges per iteration; ALL loads (8 x
// gathers + 16 u-row halves) are issued into named registers before any
// FMA, so the wave has ~24 independent VMEM ops in flight.
// ---------------------------------------------------------------------------
__global__ __launch_bounds__(256)
void gather_kernel(const int* __restrict__ src, const int* __restrict__ dst,
                   const float* __restrict__ xs0, const uint4* __restrict__ ub4,
                   float* __restrict__ out) {
    const v4i* s4 = (const v4i*)src;
    const v4i* d4 = (const v4i*)dst;

    float acc[N_CLASSES];
    #pragma unroll
    for (int c = 0; c < N_CLASSES; ++c) acc[c] = 0.0f;

    const int stride = 2048 * 256;
    int tid = blockIdx.x * 256 + threadIdx.x;

    // N_EDGES/8 groups of 8 edges; each thread handles 2 int4-pairs per iter.
    for (int i = tid; i < N_EDGES / 8; i += stride) {
        v4i sA = __builtin_nontemporal_load(s4 + 2 * i);
        v4i sB = __builtin_nontemporal_load(s4 + 2 * i + 1);
        v4i dA = __builtin_nontemporal_load(d4 + 2 * i);
        v4i dB = __builtin_nontemporal_load(d4 + 2 * i + 1);

        // ---- issue ALL gathers first (independent) ----
        float x0 = xs0[dA[0]], x1 = xs0[dA[1]], x2 = xs0[dA[2]], x3 = xs0[dA[3]];
        float x4 = xs0[dB[0]], x5 = xs0[dB[1]], x6 = xs0[dB[2]], x7 = xs0[dB[3]];

        uint4 a0 = ub4[(size_t)sA[0] * 2], b0 = ub4[(size_t)sA[0] * 2 + 1];
        uint4 a1 = ub4[(size_t)sA[1] * 2], b1 = ub4[(size_t)sA[1] * 2 + 1];
        uint4 a2 = ub4[(size_t)sA[2] * 2], b2 = ub4[(size_t)sA[2] * 2 + 1];
        uint4 a3 = ub4[(size_t)sA[3] * 2], b3 = ub4[(size_t)sA[3] * 2 + 1];
        uint4 a4 = ub4[(size_t)sB[0] * 2], b4 = ub4[(size_t)sB[0] * 2 + 1];
        uint4 a5 = ub4[(size_t)sB[1] * 2], b5 = ub4[(size_t)sB[1] * 2 + 1];
        uint4 a6 = ub4[(size_t)sB[2] * 2], b6 = ub4[(size_t)sB[2] * 2 + 1];
        uint4 a7 = ub4[(size_t)sB[3] * 2], b7 = ub4[(size_t)sB[3] * 2 + 1];

        // ---- then all FMAs (16 independent accumulator chains) ----
        #define ACCUM(A, B, X)                                                \
            acc[0]  = fmaf(bf_lo((A).x), (X), acc[0]);                        \
            acc[1]  = fmaf(bf_hi((A).x), (X), acc[1]);                        \
            acc[2]  = fmaf(bf_lo((A).y), (X), acc[2]);                        \
            acc[3]  = fmaf(bf_hi((A).y), (X), acc[3]);                        \
            acc[4]  = fmaf(bf_lo((A).z), (X), acc[4]);                        \
            acc[5]  = fmaf(bf_hi((A).z), (X), acc[5]);                        \
            acc[6]  = fmaf(bf_lo((A).w), (X), acc[6]);                        \
            acc[7]  = fmaf(bf_hi((A).w), (X), acc[7]);                        \
            acc[8]  = fmaf(bf_lo((B).x), (X), acc[8]);                        \
            acc[9]  = fmaf(bf_hi((B).x), (X), acc[9]);                        \
            acc[10] = fmaf(bf_lo((B).y), (X), acc[10]);                       \
            acc[11] = fmaf(bf_hi((B).y), (X), acc[11]);                       \
            acc[12] = fmaf(bf_lo((B).z), (X), acc[12]);                       \
            acc[13] = fmaf(bf_hi((B).z), (X), acc[13]);                       \
            acc[14] = fmaf(bf_lo((B).w), (X), acc[14]);                       \
            acc[15] = fmaf(bf_hi((B).w), (X), acc[15]);

        ACCUM(a0, b0, x0)
        ACCUM(a1, b1, x1)
        ACCUM(a2, b2, x2)
        ACCUM(a3, b3, x3)
        ACCUM(a4, b4, x4)
        ACCUM(a5, b5, x5)
        ACCUM(a6, b6, x6)
        ACCUM(a7, b7, x7)
        #undef ACCUM
    }

    // wave64 butterfly reduce each class, then block partials, then 16 atomics
    __shared__ float part[4][N_CLASSES];
    int lane = threadIdx.x & 63;
    int wid  = threadIdx.x >> 6;
    #pragma unroll
    for (int c = 0; c < N_CLASSES; ++c) {
        float v = acc[c];
        #pragma unroll
        for (int off = 32; off > 0; off >>= 1) v += __shfl_down(v, off, 64);
        if (lane == 0) part[wid][c] = v;
    }
    __syncthreads();
    if (threadIdx.x < N_CLASSES) {
        int c = threadIdx.x;
        float sum = part[0][c] + part[1][c] + part[2][c] + part[3][c];
        atomicAdd(&out[c], sum);
    }
}

// ===========================================================================
// FALLBACK PATH (ws too small): proven-correct baseline with global atomics
// ===========================================================================
__global__ void deg_kernel(const int* __restrict__ src, unsigned int* __restrict__ deg) {
    const int4* src4 = (const int4*)src;
    int stride = gridDim.x * blockDim.x;
    for (int i = blockIdx.x * blockDim.x + threadIdx.x; i < N_EDGES / 4; i += stride) {
        int4 s = src4[i];
        atomicAdd(&deg[s.x], 1u); atomicAdd(&deg[s.y], 1u);
        atomicAdd(&deg[s.z], 1u); atomicAdd(&deg[s.w], 1u);
    }
}
__global__ void scale_kernel(const float* __restrict__ feat0,
                             const unsigned int* __restrict__ deg,
                             float* __restrict__ dscale, float* __restrict__ xs0) {
    int n = blockIdx.x * blockDim.x + threadIdx.x;
    if (n < N_NODES) {
        float ds = rsqrtf((float)deg[n]);
        dscale[n] = ds;
        xs0[n] = feat0[n] * ds;
    }
}
__global__ void scatter_kernel(const int* __restrict__ src, const int* __restrict__ dst,
                               const float* __restrict__ xs0, float* __restrict__ agg0) {
    const int4* src4 = (const int4*)src;
    const int4* dst4 = (const int4*)dst;
    int stride = gridDim.x * blockDim.x;
    for (int i = blockIdx.x * blockDim.x + threadIdx.x; i < N_EDGES / 4; i += stride) {
        int4 s = src4[i]; int4 d = dst4[i];
        atomicAdd(&agg0[s.x], xs0[d.x]); atomicAdd(&agg0[s.y], xs0[d.y]);
        atomicAdd(&agg0[s.z], xs0[d.z]); atomicAdd(&agg0[s.w], xs0[d.w]);
    }
}
__global__ void dot_kernel(const float* __restrict__ agg0, const float* __restrict__ dscale,
                           const float* __restrict__ fc_w, float* __restrict__ out) {
    int n = blockIdx.x * blockDim.x + threadIdx.x;
    float y = agg0[n] * dscale[n];
    __shared__ float part[4][N_CLASSES];
    int lane = threadIdx.x & 63, wid = threadIdx.x >> 6;
    #pragma unroll
    for (int c = 0; c < N_CLASSES; ++c) {
        float v = y * fc_w[c * N_NODES + n];
        #pragma unroll
        for (int off = 32; off > 0; off >>= 1) v += __shfl_down(v, off, 64);
        if (lane == 0) part[wid][c] = v;
    }
    __syncthreads();
    if (threadIdx.x < N_CLASSES) {
        int c = threadIdx.x;
        atomicAdd(&out[c], part[0][c] + part[1][c] + part[2][c] + part[3][c]);
    }
}

// ===========================================================================
extern "C" void kernel_launch(void* const* d_in, const int* in_sizes, int n_in,
                              void* d_out, int out_size, void* d_ws, size_t ws_size,
                              hipStream_t stream) {
    const float* nodes_feat = (const float*)d_in[0];   // (B,N,1): batch0 = first N
    const float* fc_w       = (const float*)d_in[1];   // (C,N)
    const float* fc_b       = (const float*)d_in[2];   // (C,)
    const int*   edges      = (const int*)d_in[3];     // (B,2,E): graph 0 only

    const int* src = edges;
    const int* dst = edges + N_EDGES;
    float* out = (float*)d_out;

    // fast path ws: partials 32MB | ub 4MB | xs0 0.5MB
    const size_t PARTIALS_WORDS = (size_t)N_SLICES * HIST_WORDS;        // 8M u32
    const size_t U_WORDS        = (size_t)N_NODES * 8;                  // 1M u32 (bf16x2)
    const size_t NEED = (PARTIALS_WORDS + U_WORDS + N_NODES) * 4;       // ~36.5 MB

    if (ws_size >= NEED) {
        unsigned int* partials = (unsigned int*)d_ws;
        uint4* ub4 = (uint4*)((unsigned int*)d_ws + PARTIALS_WORDS);
        float* xs0 = (float*)((unsigned int*)d_ws + PARTIALS_WORDS + U_WORDS);

        hist_kernel<<<N_SLICES, 1024, 0, stream>>>(src, partials);
        reduce_finalize_kernel<<<N_NODES / 4 / 256, 256, 0, stream>>>(
            partials, nodes_feat, fc_w, ub4, xs0);
        out_init_kernel<<<1, 64, 0, stream>>>(fc_b, out);
        gather_kernel<<<2048, 256, 0, stream>>>(src, dst, xs0, ub4, out);
    } else {
        // fallback: baseline with global atomics (needs 2 MB)
        unsigned int* deg = (unsigned int*)d_ws;
        float* dscale = (float*)d_ws + N_NODES;
        float* xs0    = (float*)d_ws + 2 * N_NODES;
        float* agg0   = (float*)d_ws + 3 * N_NODES;
        hipMemsetAsync(deg, 0, N_NODES * sizeof(unsigned int), stream);
        hipMemsetAsync(agg0, 0, N_NODES * sizeof(float), stream);
        deg_kernel<<<2048, 256, 0, stream>>>(src, deg);
        scale_kernel<<<N_NODES / 256, 256, 0, stream>>>(nodes_feat, deg, dscale, xs0);
        scatter_kernel<<<2048, 256, 0, stream>>>(src, dst, xs0, agg0);
        out_init_kernel<<<1, 64, 0, stream>>>(fc_b, out);
        dot_kernel<<<N_NODES / 256, 256, 0, stream>>>(agg0, dscale, fc_w, out);
    }
}